// Round 3
// baseline (1225.032 us; speedup 1.0000x reference)
//
#include <hip/hip_runtime.h>
#include <hip/hip_bf16.h>
#include <math.h>

#define BB 4
#define LL 512
#define D0 640
#define PP 128
#define CC 32
#define NLAYER 3
#define NN (BB*LL)      // 2048
#define RADIN 130

typedef __attribute__((ext_vector_type(8))) short bf16x8;
typedef __attribute__((ext_vector_type(4))) float f32x4;

__device__ __forceinline__ short f2b(float v) {
    __hip_bfloat16 h = __float2bfloat16(v);
    short s; __builtin_memcpy(&s, &h, 2); return s;
}

// ---------------- init kernels ----------------

// h0 = seq_rep @ Win0   (one wave per node; lanes 0..31 chan, halves split K)
__global__ __launch_bounds__(64) void k_init_h0(const float* __restrict__ seq,
                                                const float* __restrict__ Win0,
                                                float* __restrict__ h0) {
    const int n = blockIdx.x, lane = threadIdx.x;
    const int c = lane & 31, half = lane >> 5;
    const float* s = seq + (size_t)n * D0;
    float acc = 0.f;
    const int i0 = half * (D0 / 2), i1 = i0 + (D0 / 2);
    for (int i = i0; i < i1; ++i) acc = fmaf(s[i], Win0[i * CC + c], acc);
    acc += __shfl_xor(acc, 32);
    if (lane < 32) h0[n * CC + c] = acc;
}

// h1[n,c,d] = x[n,d] * Win1[c]; also zero deg
__global__ void k_init_h1(const float* __restrict__ x, const float* __restrict__ Win1,
                          float* __restrict__ h1, int* __restrict__ deg) {
    int idx = blockIdx.x * blockDim.x + threadIdx.x;
    if (idx < NN) deg[idx] = 0;
    if (idx >= NN * CC) return;
    int n = idx >> 5, c = idx & 31;
    float w = Win1[c];
    const float* xp = x + n * 3;
    float* hp = h1 + (size_t)n * 96 + c * 3;
    hp[0] = xp[0] * w; hp[1] = xp[1] * w; hp[2] = xp[2] * w;
}

// fused per-edge setup: geometry + degree count + bf16 ef row [E][160]
__global__ __launch_bounds__(256) void k_edge_setup(
    const int* __restrict__ src, const int* __restrict__ dst,
    const float* __restrict__ x,
    const float* __restrict__ pair, const float* __restrict__ bppm,
    float* __restrict__ rhat, int* __restrict__ deg,
    short* __restrict__ efb, int E)
{
    int e = blockIdx.x * 4 + (threadIdx.x >> 6);
    int lane = threadIdx.x & 63;
    if (e >= E) return;
    int s = src[e], d = dst[e];
    float dx = x[d * 3 + 0] - x[s * 3 + 0];
    float dy = x[d * 3 + 1] - x[s * 3 + 1];
    float dz = x[d * 3 + 2] - x[s * 3 + 2];
    float r = sqrtf(dx * dx + dy * dy + dz * dz + 1e-12f);
    float ir = 1.f / (r + 1e-8f);
    int b = s / LL, si = s % LL, di = d % LL;
    size_t prow = ((size_t)b * LL + si) * LL + di;
    const float* pr = pair + prow * PP;
    short* out = efb + (size_t)e * 160;
    out[lane] = f2b(pr[lane]);
    out[64 + lane] = f2b(pr[64 + lane]);
    if (lane < 32) {
        float v = 0.f;
        if (lane == 0) v = bppm[prow];
        else if (lane == 1) v = r;
        out[128 + lane] = f2b(v);
    }
    if (lane < 3) rhat[e * 3 + lane] = (lane == 0 ? dx : lane == 1 ? dy : dz) * ir;
    if (lane == 0) atomicAdd(&deg[d], 1);
}

// exclusive scan over N=2048 degrees with one wave; also zero cursor
__global__ __launch_bounds__(64) void k_scan(const int* __restrict__ deg,
                                             int* __restrict__ rowptr,
                                             int* __restrict__ cursor) {
    const int lane = threadIdx.x;          // 0..63
    const int base = lane * 32;            // 64*32 = 2048
    int loc[32]; int s = 0;
    for (int i = 0; i < 32; ++i) { loc[i] = deg[base + i]; s += loc[i]; }
    int pre = s;
    for (int off = 1; off < 64; off <<= 1) {
        int t = __shfl_up(pre, off);
        if (lane >= off) pre += t;
    }
    pre -= s;
    int run = pre;
    for (int i = 0; i < 32; ++i) { rowptr[base + i] = run; cursor[base + i] = 0; run += loc[i]; }
    if (lane == 63) rowptr[NN] = run;
}

// eorder[slot] = edge id occupying dst-sorted slot
__global__ void k_scatter(const int* __restrict__ dst, const int* __restrict__ rowptr,
                          int* __restrict__ cursor, int* __restrict__ eorder, int E) {
    int e = blockIdx.x * blockDim.x + threadIdx.x;
    if (e >= E) return;
    int d = dst[e];
    int pos = atomicAdd(&cursor[d], 1);
    eorder[rowptr[d] + pos] = e;
}

// pack Wr1/Wr2 into MFMA B-fragment order (bf16)
// W1p: [NL][5][4][64][8] ; W2p: [NL][2][8][64][8]
__global__ void k_pack(const float* __restrict__ Wr1, const float* __restrict__ Wr2,
                       short* __restrict__ W1p, short* __restrict__ W2p) {
    int t = blockIdx.x * blockDim.x + threadIdx.x;
    const int tot1 = NLAYER * 5 * 4 * 64 * 8;
    const int tot2 = NLAYER * 2 * 8 * 64 * 8;
    if (t < tot1) {
        int j = t & 7; int r = t >> 3;
        int ln = r & 63; r >>= 6;
        int cb = r & 3; r >>= 2;
        int kb = r % 5; int l = r / 5;
        int row = kb * 32 + (ln >> 4) * 8 + j;
        int col = cb * 16 + (ln & 15);
        float v = (row < RADIN) ? Wr1[((size_t)l * RADIN + row) * 64 + col] : 0.f;
        W1p[t] = f2b(v);
    } else if (t < tot1 + tot2) {
        int t2 = t - tot1;
        int j = t2 & 7; int r = t2 >> 3;
        int ln = r & 63; r >>= 6;
        int cb = r & 7; r >>= 3;
        int kb = r & 1; int l = r >> 1;
        int row = kb * 32 + (ln >> 4) * 8 + j;
        int col = cb * 16 + (ln & 15);
        W2p[t2] = f2b(Wr2[((size_t)l * 64 + row) * 128 + col]);
    }
}

// ---------------- layer-0 node precompute ----------------
__global__ __launch_bounds__(256) void k_nodepre(
    int l, const float* __restrict__ h0, const float* __restrict__ h1,
    const float* __restrict__ Wq, const float* __restrict__ Wm00,
    const float* __restrict__ Wm10, const float* __restrict__ Wm11,
    float* __restrict__ qbuf, float* __restrict__ P00,
    float* __restrict__ P10, float* __restrict__ P11)
{
    __shared__ float sh0[8][32], sh1[8][96];
    const int c = threadIdx.x & 31, hw = threadIdx.x >> 5;
    const int n = blockIdx.x * 8 + hw;
    sh0[hw][c] = h0[n * CC + c];
    const float* hp = h1 + (size_t)n * 96 + c * 3;
    sh1[hw][c * 3 + 0] = hp[0]; sh1[hw][c * 3 + 1] = hp[1]; sh1[hw][c * 3 + 2] = hp[2];
    const float* WqL  = Wq   + l * 1024;
    const float* W00L = Wm00 + l * 1024;
    const float* W10L = Wm10 + l * 1024;
    const float* W11L = Wm11 + l * 1024;
    float q = 0.f, p00 = 0.f, p10 = 0.f, px = 0.f, py = 0.f, pz = 0.f;
    for (int i = 0; i < 32; ++i) {
        float a = sh0[hw][i];
        q   = fmaf(a, WqL[i * 32 + c], q);
        p00 = fmaf(a, W00L[i * 32 + c], p00);
        p10 = fmaf(a, W10L[i * 32 + c], p10);
        float w = W11L[i * 32 + c];
        px = fmaf(sh1[hw][i * 3 + 0], w, px);
        py = fmaf(sh1[hw][i * 3 + 1], w, py);
        pz = fmaf(sh1[hw][i * 3 + 2], w, pz);
    }
    qbuf[n * 32 + c] = q; P00[n * 32 + c] = p00; P10[n * 32 + c] = p10;
    float* pp = P11 + (size_t)n * 96 + c * 3;
    pp[0] = px; pp[1] = py; pp[2] = pz;
}

// ---------------- fully fused per-layer kernel ----------------
// One block per node. Loops over the node's dst-sorted incoming-edge list
// in 64-edge tiles: {gather ef rows -> MFMA radial MLP -> edge epilogue ->
// online-softmax accumulate}. Messages live only in LDS/registers.
// Then: softmax merge, h0 LayerNorm, h1 norm-gating, nodepre(l+1) or output.
// Next-layer node tensors are ping-ponged to avoid cross-block races.
__global__ __launch_bounds__(256) void k_layer(
    int l, int E,
    const int* __restrict__ rowptr, const int* __restrict__ eorder,
    const int* __restrict__ src, const float* __restrict__ rhat,
    const short* __restrict__ efb,       // [E][160] bf16
    const short* __restrict__ W1p, const short* __restrict__ W2p,
    const float* __restrict__ br1, const float* __restrict__ br2,
    const float* __restrict__ Wm01,
    const float* __restrict__ h1_in,
    const float* __restrict__ P00, const float* __restrict__ P10,
    const float* __restrict__ P11, const float* __restrict__ qbuf_in,
    float* __restrict__ h0,              // in-place (own block only)
    float* __restrict__ h1_out,
    const float* __restrict__ Ws0, const float* __restrict__ Ws1,
    const float* __restrict__ gam0, const float* __restrict__ bet0,
    const float* __restrict__ gam1,
    const float* __restrict__ Wq, const float* __restrict__ Wm00,
    const float* __restrict__ Wm10, const float* __restrict__ Wm11,
    float* __restrict__ qout, float* __restrict__ P00o,
    float* __restrict__ P10o, float* __restrict__ P11o,
    const float* __restrict__ x, const float* __restrict__ Wout,
    float* __restrict__ outp)
{
    const int n = blockIdx.x;
    const int tid = threadIdx.x;
    const int lane = tid & 63, wv = tid >> 6;
    const int r16 = lane & 15, q4 = lane >> 4;
    const int hw = tid >> 5, c = tid & 31;

    __shared__ short s_hid[4][16][72];     // per-wave GEMM1 out (bf16)
    __shared__ float s_rad[64][132];       // radial out; s_part aliases this
    __shared__ float sW[1024];             // Wm01 layer slice
    __shared__ int   s_eid[64];
    __shared__ float s_a0[32], s_a1[96];
    __shared__ float s_hn[128];            // h0n[0:32), h1n[32+c*3+d)
#define S_PART(k, cc, j) (((float*)s_rad)[(((k) * 32 + (cc)) * 6) + (j)])

    for (int i = tid; i < 1024; i += 256) sW[i] = Wm01[l * 1024 + i];

    const int st = rowptr[n], en = rowptr[n + 1];
    const float qc = qbuf_in[n * 32 + c];

    const short* b1b = W1p + (size_t)l * (5 * 4 * 64 * 8) + lane * 8;
    const short* b2b = W2p + (size_t)l * (2 * 8 * 64 * 8) + lane * 8;

    float m_run = -INFINITY, l_run = 0.f;
    float a0 = 0.f, a1x = 0.f, a1y = 0.f, a1z = 0.f;

    for (int t0 = st; t0 < en; t0 += 64) {
        __syncthreads();   // protect s_eid/s_rad from previous tile's readers
        if (tid < 64) {
            int slot = t0 + tid;
            s_eid[tid] = eorder[slot < en ? slot : en - 1];
        }
        __syncthreads();

        // ---- GEMM1: [16 x 160] @ [160 x 64] (this wave's 16 edges) ----
        f32x4 acc0 = {0.f,0.f,0.f,0.f}, acc1 = {0.f,0.f,0.f,0.f};
        f32x4 acc2 = {0.f,0.f,0.f,0.f}, acc3 = {0.f,0.f,0.f,0.f};
        {
            const int eid = s_eid[wv * 16 + r16];
            const short* arow = efb + (size_t)eid * 160 + q4 * 8;
            for (int kb = 0; kb < 5; ++kb) {
                bf16x8 af = *(const bf16x8*)(arow + kb * 32);
                const short* bp = b1b + kb * (4 * 64 * 8);
                bf16x8 b0 = *(const bf16x8*)(bp);
                bf16x8 b1v = *(const bf16x8*)(bp + 64 * 8);
                bf16x8 b2v = *(const bf16x8*)(bp + 2 * 64 * 8);
                bf16x8 b3v = *(const bf16x8*)(bp + 3 * 64 * 8);
                acc0 = __builtin_amdgcn_mfma_f32_16x16x32_bf16(af, b0,  acc0, 0, 0, 0);
                acc1 = __builtin_amdgcn_mfma_f32_16x16x32_bf16(af, b1v, acc1, 0, 0, 0);
                acc2 = __builtin_amdgcn_mfma_f32_16x16x32_bf16(af, b2v, acc2, 0, 0, 0);
                acc3 = __builtin_amdgcn_mfma_f32_16x16x32_bf16(af, b3v, acc3, 0, 0, 0);
            }
        }
        {
            f32x4 a[4] = {acc0, acc1, acc2, acc3};
            for (int cb = 0; cb < 4; ++cb) {
                int col = cb * 16 + r16;
                float b = br1[l * 64 + col];
                for (int i = 0; i < 4; ++i) {
                    float v = fmaxf(a[cb][i] + b, 0.f);
                    s_hid[wv][q4 * 4 + i][col] = f2b(v);
                }
            }
        }
        // ---- GEMM2: [16 x 64] @ [64 x 128] ----
        f32x4 o[8];
        for (int cb = 0; cb < 8; ++cb) { o[cb].x=0.f; o[cb].y=0.f; o[cb].z=0.f; o[cb].w=0.f; }
        for (int kb = 0; kb < 2; ++kb) {
            bf16x8 af = *(const bf16x8*)(&s_hid[wv][r16][kb * 32 + q4 * 8]);
            const short* bp = b2b + kb * (8 * 64 * 8);
            for (int cb = 0; cb < 8; ++cb) {
                bf16x8 bf = *(const bf16x8*)(bp + cb * (64 * 8));
                o[cb] = __builtin_amdgcn_mfma_f32_16x16x32_bf16(af, bf, o[cb], 0, 0, 0);
            }
        }
        for (int cb = 0; cb < 8; ++cb) {
            int col = cb * 16 + r16;
            float b = br2[l * 128 + col];
            for (int i = 0; i < 4; ++i) {
                s_rad[wv * 16 + q4 * 4 + i][col] = o[cb][i] + b;
            }
        }
        __syncthreads();

        // ---- epilogue + online softmax: half-wave per edge, 8 each ----
        const int base = lane & 32;
        for (int it = 0; it < 8; ++it) {
            const int el = hw * 8 + it;
            const int slot = t0 + el;
            if (slot >= en) break;
            const int e = s_eid[el];
            const int s = src[e];
            const float r0 = rhat[e * 3 + 0], r1 = rhat[e * 3 + 1], r2 = rhat[e * 3 + 2];
            const float* hp = h1_in + (size_t)s * 96 + c * 3;
            const float dot = hp[0] * r0 + hp[1] * r1 + hp[2] * r2;
            float t1 = 0.f;
            for (int i = 0; i < 32; ++i) {
                float di = __shfl(dot, base + i);
                t1 = fmaf(di, sW[i * 32 + c], t1);
            }
            const float w00 = s_rad[el][c],      w01 = s_rad[el][32 + c];
            const float w10 = s_rad[el][64 + c], w11 = s_rad[el][96 + c];
            const float kc = fmaf(w00, P00[s * 32 + c], w01 * t1);
            const float u10 = w10 * P10[s * 32 + c];
            const float* pp = P11 + (size_t)s * 96 + c * 3;
            const float mv0 = fmaf(w11, pp[0], u10 * r0);
            const float mv1 = fmaf(w11, pp[1], u10 * r1);
            const float mv2 = fmaf(w11, pp[2], u10 * r2);
            float p = qc * kc;
            p += __shfl_xor(p, 1); p += __shfl_xor(p, 2); p += __shfl_xor(p, 4);
            const float logit = p * 0.35355339059327373f;   // 1/sqrt(8)
            const float mn = fmaxf(m_run, logit);
            const float sc = __expf(m_run - mn);
            const float w  = __expf(logit - mn);
            l_run = fmaf(l_run, sc, w);
            a0  = fmaf(a0,  sc, w * kc);
            a1x = fmaf(a1x, sc, w * mv0);
            a1y = fmaf(a1y, sc, w * mv1);
            a1z = fmaf(a1z, sc, w * mv2);
            m_run = mn;
        }
    }

    __syncthreads();   // s_rad reads done; reuse as s_part
    S_PART(hw, c, 0) = m_run; S_PART(hw, c, 1) = l_run;
    S_PART(hw, c, 2) = a0;
    S_PART(hw, c, 3) = a1x; S_PART(hw, c, 4) = a1y; S_PART(hw, c, 5) = a1z;
    __syncthreads();

    if (tid < 32) {
        // 8-way online-softmax merge per channel
        float M = S_PART(0, c, 0), L = S_PART(0, c, 1), A0 = S_PART(0, c, 2);
        float Ax = S_PART(0, c, 3), Ay = S_PART(0, c, 4), Az = S_PART(0, c, 5);
        for (int k = 1; k < 8; ++k) {
            const float m2 = S_PART(k, c, 0);
            if (m2 == -INFINITY) continue;
            const float mn = fmaxf(M, m2);
            const float sa = (M == -INFINITY) ? 0.f : __expf(M - mn);
            const float sb = __expf(m2 - mn);
            L  = L  * sa + S_PART(k, c, 1) * sb;
            A0 = A0 * sa + S_PART(k, c, 2) * sb;
            Ax = Ax * sa + S_PART(k, c, 3) * sb;
            Ay = Ay * sa + S_PART(k, c, 4) * sb;
            Az = Az * sa + S_PART(k, c, 5) * sb;
            M = mn;
        }
        const float inv = 1.0f / (L + 1e-9f);
        s_a0[c] = A0 * inv;
        s_a1[c * 3 + 0] = Ax * inv;
        s_a1[c * 3 + 1] = Ay * inv;
        s_a1[c * 3 + 2] = Az * inv;
    }
    __syncthreads();

    if (tid < 32) {
        // ---- h0 update + LayerNorm ----
        float x0 = h0[n * CC + c];
        {
            const float* W = Ws0 + l * 1024;
            for (int i = 0; i < 32; ++i) x0 = fmaf(s_a0[i], W[i * 32 + c], x0);
        }
        float mu = x0;
        mu += __shfl_xor(mu, 1); mu += __shfl_xor(mu, 2); mu += __shfl_xor(mu, 4);
        mu += __shfl_xor(mu, 8); mu += __shfl_xor(mu, 16);
        mu *= (1.f / 32.f);
        float sq = x0 * x0;
        sq += __shfl_xor(sq, 1); sq += __shfl_xor(sq, 2); sq += __shfl_xor(sq, 4);
        sq += __shfl_xor(sq, 8); sq += __shfl_xor(sq, 16);
        float var = sq * (1.f / 32.f) - mu * mu;
        float h0n = (x0 - mu) * rsqrtf(var + 1e-5f) * gam0[l * 32 + c] + bet0[l * 32 + c];
        s_hn[c] = h0n;
        if (l + 1 < NLAYER) h0[n * CC + c] = h0n;

        // ---- h1 update + norm-gating ----
        const float* hp = h1_in + (size_t)n * 96 + c * 3;
        float v0 = hp[0], v1 = hp[1], v2 = hp[2];
        {
            const float* W = Ws1 + l * 1024;
            for (int i = 0; i < 32; ++i) {
                float w = W[i * 32 + c];
                v0 = fmaf(s_a1[i * 3 + 0], w, v0);
                v1 = fmaf(s_a1[i * 3 + 1], w, v1);
                v2 = fmaf(s_a1[i * 3 + 2], w, v2);
            }
        }
        float nrm = sqrtf(v0 * v0 + v1 * v1 + v2 * v2 + 1e-12f);
        float mu2 = nrm;
        mu2 += __shfl_xor(mu2, 1); mu2 += __shfl_xor(mu2, 2); mu2 += __shfl_xor(mu2, 4);
        mu2 += __shfl_xor(mu2, 8); mu2 += __shfl_xor(mu2, 16);
        mu2 *= (1.f / 32.f);
        float sq2 = nrm * nrm;
        sq2 += __shfl_xor(sq2, 1); sq2 += __shfl_xor(sq2, 2); sq2 += __shfl_xor(sq2, 4);
        sq2 += __shfl_xor(sq2, 8); sq2 += __shfl_xor(sq2, 16);
        float var2 = sq2 * (1.f / 32.f) - mu2 * mu2;
        float nln = (nrm - mu2) * rsqrtf(var2 + 1e-5f) * gam1[l * 32 + c];
        float scl = nln / (nrm + 1e-8f);
        float w0 = v0 * scl, w1 = v1 * scl, w2 = v2 * scl;
        s_hn[32 + c * 3 + 0] = w0;
        s_hn[32 + c * 3 + 1] = w1;
        s_hn[32 + c * 3 + 2] = w2;
        if (l + 1 < NLAYER) {
            float* hq = h1_out + (size_t)n * 96 + c * 3;
            hq[0] = w0; hq[1] = w1; hq[2] = w2;
        } else {
            // ---- fused output projection: out = x + h1n . Wout ----
            const float wo = Wout[c];
            float d0 = w0 * wo, d1 = w1 * wo, d2 = w2 * wo;
            d0 += __shfl_xor(d0, 1); d1 += __shfl_xor(d1, 1); d2 += __shfl_xor(d2, 1);
            d0 += __shfl_xor(d0, 2); d1 += __shfl_xor(d1, 2); d2 += __shfl_xor(d2, 2);
            d0 += __shfl_xor(d0, 4); d1 += __shfl_xor(d1, 4); d2 += __shfl_xor(d2, 4);
            d0 += __shfl_xor(d0, 8); d1 += __shfl_xor(d1, 8); d2 += __shfl_xor(d2, 8);
            d0 += __shfl_xor(d0, 16); d1 += __shfl_xor(d1, 16); d2 += __shfl_xor(d2, 16);
            if (c == 0) {
                outp[n * 3 + 0] = x[n * 3 + 0] + d0;
                outp[n * 3 + 1] = x[n * 3 + 1] + d1;
                outp[n * 3 + 2] = x[n * 3 + 2] + d2;
            }
        }
    }

    if (l + 1 < NLAYER) {
        __syncthreads();
        // ---- fused nodepre for layer l+1: 4 groups of 32 lanes ----
        const int grp = tid >> 5;
        if (grp < 4) {
            const int lp = l + 1;
            if (grp == 0) {
                const float* W = Wq + lp * 1024;
                float acc = 0.f;
                for (int i = 0; i < 32; ++i) acc = fmaf(s_hn[i], W[i * 32 + c], acc);
                qout[n * 32 + c] = acc;
            } else if (grp == 1) {
                const float* W = Wm00 + lp * 1024;
                float acc = 0.f;
                for (int i = 0; i < 32; ++i) acc = fmaf(s_hn[i], W[i * 32 + c], acc);
                P00o[n * 32 + c] = acc;
            } else if (grp == 2) {
                const float* W = Wm10 + lp * 1024;
                float acc = 0.f;
                for (int i = 0; i < 32; ++i) acc = fmaf(s_hn[i], W[i * 32 + c], acc);
                P10o[n * 32 + c] = acc;
            } else {
                const float* W = Wm11 + lp * 1024;
                float px = 0.f, py = 0.f, pz = 0.f;
                for (int i = 0; i < 32; ++i) {
                    float w = W[i * 32 + c];
                    px = fmaf(s_hn[32 + i * 3 + 0], w, px);
                    py = fmaf(s_hn[32 + i * 3 + 1], w, py);
                    pz = fmaf(s_hn[32 + i * 3 + 2], w, pz);
                }
                float* pp = P11o + (size_t)n * 96 + c * 3;
                pp[0] = px; pp[1] = py; pp[2] = pz;
            }
        }
    }
#undef S_PART
}

// ---------------- launch ----------------
extern "C" void kernel_launch(void* const* d_in, const int* in_sizes, int n_in,
                              void* d_out, int out_size, void* d_ws, size_t ws_size,
                              hipStream_t stream) {
    const float* seq  = (const float*)d_in[0];
    const float* pair = (const float*)d_in[1];
    const float* bppm = (const float*)d_in[2];
    const float* x    = (const float*)d_in[3];
    const int*   src  = (const int*)d_in[4];
    const int*   dst  = (const int*)d_in[5];
    const float* Win0 = (const float*)d_in[6];
    const float* Win1 = (const float*)d_in[7];
    const float* Wr1  = (const float*)d_in[8];
    const float* br1  = (const float*)d_in[9];
    const float* Wr2  = (const float*)d_in[10];
    const float* br2  = (const float*)d_in[11];
    const float* Wm00 = (const float*)d_in[12];
    const float* Wm01 = (const float*)d_in[13];
    const float* Wm10 = (const float*)d_in[14];
    const float* Wm11 = (const float*)d_in[15];
    const float* Wq   = (const float*)d_in[16];
    const float* Ws0  = (const float*)d_in[17];
    const float* Ws1  = (const float*)d_in[18];
    const float* gam0 = (const float*)d_in[19];
    const float* bet0 = (const float*)d_in[20];
    const float* gam1 = (const float*)d_in[21];
    const float* Wout = (const float*)d_in[22];
    const int E = in_sizes[4];

    char* w = (char*)d_ws;
    auto alloc = [&](size_t nbytes) {
        void* p = (void*)w;
        w += (nbytes + 255) & ~(size_t)255;
        return p;
    };
    float* h0    = (float*)alloc((size_t)NN * CC * 4);
    float* h1a   = (float*)alloc((size_t)NN * 96 * 4);
    float* h1b   = (float*)alloc((size_t)NN * 96 * 4);
    float* rhat  = (float*)alloc((size_t)E * 3 * 4);
    int* deg     = (int*)alloc((size_t)NN * 4);
    int* rowptr  = (int*)alloc((size_t)(NN + 1) * 4);
    int* cursor  = (int*)alloc((size_t)NN * 4);
    int* eorder  = (int*)alloc((size_t)E * 4);
    short* efb   = (short*)alloc((size_t)E * 160 * 2);
    short* W1p   = (short*)alloc((size_t)NLAYER * 5 * 4 * 64 * 8 * 2);
    short* W2p   = (short*)alloc((size_t)NLAYER * 2 * 8 * 64 * 8 * 2);
    float* qbufA = (float*)alloc((size_t)NN * 32 * 4);
    float* qbufB = (float*)alloc((size_t)NN * 32 * 4);
    float* P00A  = (float*)alloc((size_t)NN * 32 * 4);
    float* P00B  = (float*)alloc((size_t)NN * 32 * 4);
    float* P10A  = (float*)alloc((size_t)NN * 32 * 4);
    float* P10B  = (float*)alloc((size_t)NN * 32 * 4);
    float* P11A  = (float*)alloc((size_t)NN * 96 * 4);
    float* P11B  = (float*)alloc((size_t)NN * 96 * 4);

    float* h1_[2]  = {h1a, h1b};
    float* q_[2]   = {qbufA, qbufB};
    float* p00_[2] = {P00A, P00B};
    float* p10_[2] = {P10A, P10B};
    float* p11_[2] = {P11A, P11B};

    const int TB = 256;
    k_init_h0<<<NN, 64, 0, stream>>>(seq, Win0, h0);
    k_init_h1<<<(NN * CC + TB - 1) / TB, TB, 0, stream>>>(x, Win1, h1a, deg);
    k_edge_setup<<<(E + 3) / 4, 256, 0, stream>>>(src, dst, x, pair, bppm,
                                                  rhat, deg, efb, E);
    k_scan<<<1, 64, 0, stream>>>(deg, rowptr, cursor);
    k_scatter<<<(E + TB - 1) / TB, TB, 0, stream>>>(dst, rowptr, cursor, eorder, E);
    {
        int tot = NLAYER * 5 * 4 * 64 * 8 + NLAYER * 2 * 8 * 64 * 8;
        k_pack<<<(tot + TB - 1) / TB, TB, 0, stream>>>(Wr1, Wr2, W1p, W2p);
    }
    k_nodepre<<<NN / 8, 256, 0, stream>>>(0, h0, h1a, Wq, Wm00, Wm10, Wm11,
                                          qbufA, P00A, P10A, P11A);

    for (int l = 0; l < NLAYER; ++l) {
        const int in = l & 1, out = (l + 1) & 1;
        k_layer<<<NN, 256, 0, stream>>>(
            l, E, rowptr, eorder, src, rhat, efb, W1p, W2p, br1, br2,
            Wm01, h1_[in], p00_[in], p10_[in], p11_[in], q_[in],
            h0, h1_[out],
            Ws0, Ws1, gam0, bet0, gam1,
            Wq, Wm00, Wm10, Wm11,
            q_[out], p00_[out], p10_[out], p11_[out],
            x, Wout, (float*)d_out);
    }
}

// Round 4
// 834.609 us; speedup vs baseline: 1.4678x; 1.4678x over previous
//
#include <hip/hip_runtime.h>
#include <hip/hip_bf16.h>
#include <hip/hip_fp16.h>
#include <math.h>

#define BB 4
#define LL 512
#define D0 640
#define PP 128
#define CC 32
#define NLAYER 3
#define NN (BB*LL)      // 2048
#define RADIN 130

typedef __attribute__((ext_vector_type(8))) short bf16x8;
typedef __attribute__((ext_vector_type(4))) float f32x4;

__device__ __forceinline__ short f2b(float v) {
    __hip_bfloat16 h = __float2bfloat16(v);
    short s; __builtin_memcpy(&s, &h, 2); return s;
}
__device__ __forceinline__ unsigned short f2h(float v) {
    __half h = __float2half(v);
    unsigned short s; __builtin_memcpy(&s, &h, 2); return s;
}
__device__ __forceinline__ float h2f(unsigned short s) {
    __half h; __builtin_memcpy(&h, &s, 2); return __half2float(h);
}

// ---------------- init kernels ----------------

// h0 = seq_rep @ Win0   (one wave per node; lanes 0..31 chan, halves split K)
__global__ __launch_bounds__(64) void k_init_h0(const float* __restrict__ seq,
                                                const float* __restrict__ Win0,
                                                float* __restrict__ h0) {
    const int n = blockIdx.x, lane = threadIdx.x;
    const int c = lane & 31, half = lane >> 5;
    const float* s = seq + (size_t)n * D0;
    float acc = 0.f;
    const int i0 = half * (D0 / 2), i1 = i0 + (D0 / 2);
    for (int i = i0; i < i1; ++i) acc = fmaf(s[i], Win0[i * CC + c], acc);
    acc += __shfl_xor(acc, 32);
    if (lane < 32) h0[n * CC + c] = acc;
}

// h1[n,c,d] = x[n,d] * Win1[c]; also zero deg
__global__ void k_init_h1(const float* __restrict__ x, const float* __restrict__ Win1,
                          float* __restrict__ h1, int* __restrict__ deg) {
    int idx = blockIdx.x * blockDim.x + threadIdx.x;
    if (idx < NN) deg[idx] = 0;
    if (idx >= NN * CC) return;
    int n = idx >> 5, c = idx & 31;
    float w = Win1[c];
    const float* xp = x + n * 3;
    float* hp = h1 + (size_t)n * 96 + c * 3;
    hp[0] = xp[0] * w; hp[1] = xp[1] * w; hp[2] = xp[2] * w;
}

// fused per-edge setup: geometry + degree count + bf16 ef row [E][160]
__global__ __launch_bounds__(256) void k_edge_setup(
    const int* __restrict__ src, const int* __restrict__ dst,
    const float* __restrict__ x,
    const float* __restrict__ pair, const float* __restrict__ bppm,
    float* __restrict__ rhat, int* __restrict__ deg,
    short* __restrict__ efb, int E)
{
    int e = blockIdx.x * 4 + (threadIdx.x >> 6);
    int lane = threadIdx.x & 63;
    if (e >= E) return;
    int s = src[e], d = dst[e];
    float dx = x[d * 3 + 0] - x[s * 3 + 0];
    float dy = x[d * 3 + 1] - x[s * 3 + 1];
    float dz = x[d * 3 + 2] - x[s * 3 + 2];
    float r = sqrtf(dx * dx + dy * dy + dz * dz + 1e-12f);
    float ir = 1.f / (r + 1e-8f);
    int b = s / LL, si = s % LL, di = d % LL;
    size_t prow = ((size_t)b * LL + si) * LL + di;
    const float* pr = pair + prow * PP;
    short* out = efb + (size_t)e * 160;
    out[lane] = f2b(pr[lane]);
    out[64 + lane] = f2b(pr[64 + lane]);
    if (lane < 32) {
        float v = 0.f;
        if (lane == 0) v = bppm[prow];
        else if (lane == 1) v = r;
        out[128 + lane] = f2b(v);
    }
    if (lane < 3) rhat[e * 3 + lane] = (lane == 0 ? dx : lane == 1 ? dy : dz) * ir;
    if (lane == 0) atomicAdd(&deg[d], 1);
}

// exclusive scan over N=2048 degrees with one wave; also zero cursor
__global__ __launch_bounds__(64) void k_scan(const int* __restrict__ deg,
                                             int* __restrict__ rowptr,
                                             int* __restrict__ cursor) {
    const int lane = threadIdx.x;          // 0..63
    const int base = lane * 32;            // 64*32 = 2048
    int loc[32]; int s = 0;
    for (int i = 0; i < 32; ++i) { loc[i] = deg[base + i]; s += loc[i]; }
    int pre = s;
    for (int off = 1; off < 64; off <<= 1) {
        int t = __shfl_up(pre, off);
        if (lane >= off) pre += t;
    }
    pre -= s;
    int run = pre;
    for (int i = 0; i < 32; ++i) { rowptr[base + i] = run; cursor[base + i] = 0; run += loc[i]; }
    if (lane == 63) rowptr[NN] = run;
}

// eperm[e] = dst-sorted slot of edge e (producer-side scatter position)
__global__ void k_scatter(const int* __restrict__ dst, const int* __restrict__ rowptr,
                          int* __restrict__ cursor, int* __restrict__ eperm, int E) {
    int e = blockIdx.x * blockDim.x + threadIdx.x;
    if (e >= E) return;
    int d = dst[e];
    int pos = atomicAdd(&cursor[d], 1);
    eperm[e] = rowptr[d] + pos;
}

// pack Wr1/Wr2 into MFMA B-fragment order (bf16)
// W1p: [NL][5][4][64][8] ; W2p: [NL][2][8][64][8]
__global__ void k_pack(const float* __restrict__ Wr1, const float* __restrict__ Wr2,
                       short* __restrict__ W1p, short* __restrict__ W2p) {
    int t = blockIdx.x * blockDim.x + threadIdx.x;
    const int tot1 = NLAYER * 5 * 4 * 64 * 8;
    const int tot2 = NLAYER * 2 * 8 * 64 * 8;
    if (t < tot1) {
        int j = t & 7; int r = t >> 3;
        int ln = r & 63; r >>= 6;
        int cb = r & 3; r >>= 2;
        int kb = r % 5; int l = r / 5;
        int row = kb * 32 + (ln >> 4) * 8 + j;
        int col = cb * 16 + (ln & 15);
        float v = (row < RADIN) ? Wr1[((size_t)l * RADIN + row) * 64 + col] : 0.f;
        W1p[t] = f2b(v);
    } else if (t < tot1 + tot2) {
        int t2 = t - tot1;
        int j = t2 & 7; int r = t2 >> 3;
        int ln = r & 63; r >>= 6;
        int cb = r & 7; r >>= 3;
        int kb = r & 1; int l = r >> 1;
        int row = kb * 32 + (ln >> 4) * 8 + j;
        int col = cb * 16 + (ln & 15);
        W2p[t2] = f2b(Wr2[((size_t)l * 64 + row) * 128 + col]);
    }
}

// ---------------- layer-0 node precompute ----------------
__global__ __launch_bounds__(256) void k_nodepre(
    int l, const float* __restrict__ h0, const float* __restrict__ h1,
    const float* __restrict__ Wq, const float* __restrict__ Wm00,
    const float* __restrict__ Wm10, const float* __restrict__ Wm11,
    float* __restrict__ qbuf, float* __restrict__ P00,
    float* __restrict__ P10, float* __restrict__ P11)
{
    __shared__ float sh0[8][32], sh1[8][96];
    const int c = threadIdx.x & 31, hw = threadIdx.x >> 5;
    const int n = blockIdx.x * 8 + hw;
    sh0[hw][c] = h0[n * CC + c];
    const float* hp = h1 + (size_t)n * 96 + c * 3;
    sh1[hw][c * 3 + 0] = hp[0]; sh1[hw][c * 3 + 1] = hp[1]; sh1[hw][c * 3 + 2] = hp[2];
    const float* WqL  = Wq   + l * 1024;
    const float* W00L = Wm00 + l * 1024;
    const float* W10L = Wm10 + l * 1024;
    const float* W11L = Wm11 + l * 1024;
    float q = 0.f, p00 = 0.f, p10 = 0.f, px = 0.f, py = 0.f, pz = 0.f;
    for (int i = 0; i < 32; ++i) {
        float a = sh0[hw][i];
        q   = fmaf(a, WqL[i * 32 + c], q);
        p00 = fmaf(a, W00L[i * 32 + c], p00);
        p10 = fmaf(a, W10L[i * 32 + c], p10);
        float w = W11L[i * 32 + c];
        px = fmaf(sh1[hw][i * 3 + 0], w, px);
        py = fmaf(sh1[hw][i * 3 + 1], w, py);
        pz = fmaf(sh1[hw][i * 3 + 2], w, pz);
    }
    qbuf[n * 32 + c] = q; P00[n * 32 + c] = p00; P10[n * 32 + c] = p10;
    float* pp = P11 + (size_t)n * 96 + c * 3;
    pp[0] = px; pp[1] = py; pp[2] = pz;
}

// ---------------- fused radial MLP + edge epilogue ----------------
__global__ __launch_bounds__(256) void k_radedge(
    int l, int E,
    const int* __restrict__ src,
    const float* __restrict__ rhat,
    const short* __restrict__ efb,       // [E][160] bf16
    const short* __restrict__ W1p,       // [NL][5][4][64][8]
    const short* __restrict__ W2p,       // [NL][2][8][64][8]
    const float* __restrict__ br1,       // [NL][64]
    const float* __restrict__ br2,       // [NL][128]
    const float* __restrict__ Wm01,
    const float* __restrict__ h1,
    const float* __restrict__ P00,
    const float* __restrict__ P10,
    const float* __restrict__ P11,
    const int* __restrict__ eperm,
    unsigned short* __restrict__ mbuf)   // [E][128] fp16: [0:32)=m0, [32+c*3+d]=m1
{
    __shared__ short s_hid[4][16][72];   // per-wave [16][64] padded to 72
    __shared__ float s_rad[64][132];     // 64 edges x 128 rad vals, padded
    __shared__ float sW[1024];           // Wm01 layer slice
    const int lane = threadIdx.x & 63, wv = threadIdx.x >> 6;
    const int r16 = lane & 15, q4 = lane >> 4;
    const int eb = blockIdx.x * 64;
    const int e0 = eb + wv * 16;

    for (int i = threadIdx.x; i < 1024; i += 256) sW[i] = Wm01[l * 1024 + i];

    // ---- GEMM1: [16 x 160] @ [160 x 64] ----
    f32x4 acc0 = {0.f,0.f,0.f,0.f}, acc1 = {0.f,0.f,0.f,0.f};
    f32x4 acc2 = {0.f,0.f,0.f,0.f}, acc3 = {0.f,0.f,0.f,0.f};
    int row = e0 + r16; if (row >= E) row = E - 1;
    const short* arow = efb + (size_t)row * 160 + q4 * 8;
    const short* b1b = W1p + (size_t)l * (5 * 4 * 64 * 8) + lane * 8;
    for (int kb = 0; kb < 5; ++kb) {
        bf16x8 af = *(const bf16x8*)(arow + kb * 32);
        const short* bp = b1b + kb * (4 * 64 * 8);
        bf16x8 b0 = *(const bf16x8*)(bp);
        bf16x8 b1v = *(const bf16x8*)(bp + 64 * 8);
        bf16x8 b2v = *(const bf16x8*)(bp + 2 * 64 * 8);
        bf16x8 b3v = *(const bf16x8*)(bp + 3 * 64 * 8);
        acc0 = __builtin_amdgcn_mfma_f32_16x16x32_bf16(af, b0,  acc0, 0, 0, 0);
        acc1 = __builtin_amdgcn_mfma_f32_16x16x32_bf16(af, b1v, acc1, 0, 0, 0);
        acc2 = __builtin_amdgcn_mfma_f32_16x16x32_bf16(af, b2v, acc2, 0, 0, 0);
        acc3 = __builtin_amdgcn_mfma_f32_16x16x32_bf16(af, b3v, acc3, 0, 0, 0);
    }
    {
        f32x4 a[4] = {acc0, acc1, acc2, acc3};
        for (int cb = 0; cb < 4; ++cb) {
            int col = cb * 16 + r16;
            float b = br1[l * 64 + col];
            for (int i = 0; i < 4; ++i) {
                float v = fmaxf(a[cb][i] + b, 0.f);
                s_hid[wv][q4 * 4 + i][col] = f2b(v);
            }
        }
    }
    // ---- GEMM2: [16 x 64] @ [64 x 128] ----
    f32x4 o[8];
    for (int cb = 0; cb < 8; ++cb) { o[cb].x=0.f; o[cb].y=0.f; o[cb].z=0.f; o[cb].w=0.f; }
    const short* b2b = W2p + (size_t)l * (2 * 8 * 64 * 8) + lane * 8;
    for (int kb = 0; kb < 2; ++kb) {
        bf16x8 af = *(const bf16x8*)(&s_hid[wv][r16][kb * 32 + q4 * 8]);
        const short* bp = b2b + kb * (8 * 64 * 8);
        for (int cb = 0; cb < 8; ++cb) {
            bf16x8 bf = *(const bf16x8*)(bp + cb * (64 * 8));
            o[cb] = __builtin_amdgcn_mfma_f32_16x16x32_bf16(af, bf, o[cb], 0, 0, 0);
        }
    }
    for (int cb = 0; cb < 8; ++cb) {
        int col = cb * 16 + r16;
        float b = br2[l * 128 + col];
        for (int i = 0; i < 4; ++i) {
            s_rad[wv * 16 + q4 * 4 + i][col] = o[cb][i] + b;
        }
    }
    __syncthreads();

    // ---- edge epilogue: half-wave per edge, 8 edges per half-wave ----
    const int hw = threadIdx.x >> 5;     // 0..7
    const int c = lane & 31;
    const int base = lane & 32;
    for (int it = 0; it < 8; ++it) {
        const int el = hw * 8 + it;
        const int e = eb + el;
        if (e >= E) break;
        const int s = src[e];
        const float r0 = rhat[e * 3 + 0], r1 = rhat[e * 3 + 1], r2 = rhat[e * 3 + 2];
        const float* hp = h1 + (size_t)s * 96 + c * 3;
        const float dot = hp[0] * r0 + hp[1] * r1 + hp[2] * r2;
        float t1 = 0.f;
        for (int i = 0; i < 32; ++i) {
            float di = __shfl(dot, base + i);
            t1 = fmaf(di, sW[i * 32 + c], t1);
        }
        const float w00 = s_rad[el][c],      w01 = s_rad[el][32 + c];
        const float w10 = s_rad[el][64 + c], w11 = s_rad[el][96 + c];
        const float m0 = fmaf(w00, P00[s * 32 + c], w01 * t1);
        const float u10 = w10 * P10[s * 32 + c];
        const float* pp = P11 + (size_t)s * 96 + c * 3;
        unsigned short* mp = mbuf + (size_t)eperm[e] * 128;
        mp[c] = f2h(m0);
        mp[32 + c * 3 + 0] = f2h(fmaf(w11, pp[0], u10 * r0));
        mp[32 + c * 3 + 1] = f2h(fmaf(w11, pp[1], u10 * r1));
        mp[32 + c * 3 + 2] = f2h(fmaf(w11, pp[2], u10 * r2));
    }
}

// ---------------- node update kernel (per layer) ----------------
// 256 threads = 8 half-waves, 8 edges in flight. Fuses:
//  - attention + aggregation (dst-sorted fp16 mbuf rows)
//  - h0 LayerNorm + h1 norm-gating
//  - nodepre for layer l+1 (q/P00/P10/P11)   [when l+1 < NLAYER]
//  - final output projection                  [when l == NLAYER-1]
__global__ __launch_bounds__(256) void k_node(
    int l, const int* __restrict__ rowptr,
    const unsigned short* __restrict__ mbuf,
    const float* __restrict__ qbuf_in,
    float* __restrict__ h0, float* __restrict__ h1,
    const float* __restrict__ Ws0, const float* __restrict__ Ws1,
    const float* __restrict__ gam0, const float* __restrict__ bet0,
    const float* __restrict__ gam1,
    const float* __restrict__ Wq, const float* __restrict__ Wm00,
    const float* __restrict__ Wm10, const float* __restrict__ Wm11,
    float* __restrict__ qout, float* __restrict__ P00,
    float* __restrict__ P10, float* __restrict__ P11,
    const float* __restrict__ x, const float* __restrict__ Wout,
    float* __restrict__ outp)
{
    const int n = blockIdx.x;
    const int tid = threadIdx.x;
    const int hw = tid >> 5;        // 0..7
    const int c = tid & 31;
    __shared__ float s_part[8][32][6];   // per-half-wave online-softmax partials
    __shared__ float s_a0[32], s_a1[96];
    __shared__ float s_hn[128];          // h0n[0:32), h1n[32+c*3+d]

    const float qc = qbuf_in[n * 32 + c];
    const int st = rowptr[n], en = rowptr[n + 1];

    float m_run = -INFINITY, l_run = 0.f;
    float a0 = 0.f, a1x = 0.f, a1y = 0.f, a1z = 0.f;
    for (int idx = st + hw; idx < en; idx += 8) {
        const unsigned short* row = mbuf + (size_t)idx * 128;
        const float kc = h2f(row[c]);
        const float mv0 = h2f(row[32 + c * 3 + 0]);
        const float mv1 = h2f(row[32 + c * 3 + 1]);
        const float mv2 = h2f(row[32 + c * 3 + 2]);
        float p = qc * kc;
        p += __shfl_xor(p, 1); p += __shfl_xor(p, 2); p += __shfl_xor(p, 4);
        const float logit = p * 0.35355339059327373f;   // 1/sqrt(8)
        const float mn = fmaxf(m_run, logit);
        const float sc = __expf(m_run - mn);
        const float w  = __expf(logit - mn);
        l_run = fmaf(l_run, sc, w);
        a0  = fmaf(a0,  sc, w * kc);
        a1x = fmaf(a1x, sc, w * mv0);
        a1y = fmaf(a1y, sc, w * mv1);
        a1z = fmaf(a1z, sc, w * mv2);
        m_run = mn;
    }
    s_part[hw][c][0] = m_run; s_part[hw][c][1] = l_run;
    s_part[hw][c][2] = a0;
    s_part[hw][c][3] = a1x; s_part[hw][c][4] = a1y; s_part[hw][c][5] = a1z;
    __syncthreads();

    if (tid < 32) {
        // 8-way online-softmax merge per channel
        float M = s_part[0][c][0], L = s_part[0][c][1], A0 = s_part[0][c][2];
        float Ax = s_part[0][c][3], Ay = s_part[0][c][4], Az = s_part[0][c][5];
        for (int k = 1; k < 8; ++k) {
            const float m2 = s_part[k][c][0];
            if (m2 == -INFINITY) continue;
            const float mn = fmaxf(M, m2);
            const float sa = (M == -INFINITY) ? 0.f : __expf(M - mn);
            const float sb = __expf(m2 - mn);
            L  = L  * sa + s_part[k][c][1] * sb;
            A0 = A0 * sa + s_part[k][c][2] * sb;
            Ax = Ax * sa + s_part[k][c][3] * sb;
            Ay = Ay * sa + s_part[k][c][4] * sb;
            Az = Az * sa + s_part[k][c][5] * sb;
            M = mn;
        }
        const float inv = 1.0f / (L + 1e-9f);
        s_a0[c] = A0 * inv;
        s_a1[c * 3 + 0] = Ax * inv;
        s_a1[c * 3 + 1] = Ay * inv;
        s_a1[c * 3 + 2] = Az * inv;
    }
    __syncthreads();

    if (tid < 32) {
        // ---- h0 update + LayerNorm ----
        float x0 = h0[n * CC + c];
        {
            const float* W = Ws0 + l * 1024;
            for (int i = 0; i < 32; ++i) x0 = fmaf(s_a0[i], W[i * 32 + c], x0);
        }
        float mu = x0;
        mu += __shfl_xor(mu, 1); mu += __shfl_xor(mu, 2); mu += __shfl_xor(mu, 4);
        mu += __shfl_xor(mu, 8); mu += __shfl_xor(mu, 16);
        mu *= (1.f / 32.f);
        float sq = x0 * x0;
        sq += __shfl_xor(sq, 1); sq += __shfl_xor(sq, 2); sq += __shfl_xor(sq, 4);
        sq += __shfl_xor(sq, 8); sq += __shfl_xor(sq, 16);
        float var = sq * (1.f / 32.f) - mu * mu;
        float h0n = (x0 - mu) * rsqrtf(var + 1e-5f) * gam0[l * 32 + c] + bet0[l * 32 + c];
        s_hn[c] = h0n;
        if (l + 1 < NLAYER) h0[n * CC + c] = h0n;

        // ---- h1 update + norm-gating ----
        const float* hp = h1 + (size_t)n * 96 + c * 3;
        float v0 = hp[0], v1 = hp[1], v2 = hp[2];
        {
            const float* W = Ws1 + l * 1024;
            for (int i = 0; i < 32; ++i) {
                float w = W[i * 32 + c];
                v0 = fmaf(s_a1[i * 3 + 0], w, v0);
                v1 = fmaf(s_a1[i * 3 + 1], w, v1);
                v2 = fmaf(s_a1[i * 3 + 2], w, v2);
            }
        }
        float nrm = sqrtf(v0 * v0 + v1 * v1 + v2 * v2 + 1e-12f);
        float mu2 = nrm;
        mu2 += __shfl_xor(mu2, 1); mu2 += __shfl_xor(mu2, 2); mu2 += __shfl_xor(mu2, 4);
        mu2 += __shfl_xor(mu2, 8); mu2 += __shfl_xor(mu2, 16);
        mu2 *= (1.f / 32.f);
        float sq2 = nrm * nrm;
        sq2 += __shfl_xor(sq2, 1); sq2 += __shfl_xor(sq2, 2); sq2 += __shfl_xor(sq2, 4);
        sq2 += __shfl_xor(sq2, 8); sq2 += __shfl_xor(sq2, 16);
        float var2 = sq2 * (1.f / 32.f) - mu2 * mu2;
        float nln = (nrm - mu2) * rsqrtf(var2 + 1e-5f) * gam1[l * 32 + c];
        float scl = nln / (nrm + 1e-8f);
        float w0 = v0 * scl, w1 = v1 * scl, w2 = v2 * scl;
        s_hn[32 + c * 3 + 0] = w0;
        s_hn[32 + c * 3 + 1] = w1;
        s_hn[32 + c * 3 + 2] = w2;
        if (l + 1 < NLAYER) {
            float* hq = h1 + (size_t)n * 96 + c * 3;
            hq[0] = w0; hq[1] = w1; hq[2] = w2;
        } else {
            // ---- fused output projection: out = x + h1n . Wout ----
            const float wo = Wout[c];
            float d0 = w0 * wo, d1 = w1 * wo, d2 = w2 * wo;
            d0 += __shfl_xor(d0, 1); d1 += __shfl_xor(d1, 1); d2 += __shfl_xor(d2, 1);
            d0 += __shfl_xor(d0, 2); d1 += __shfl_xor(d1, 2); d2 += __shfl_xor(d2, 2);
            d0 += __shfl_xor(d0, 4); d1 += __shfl_xor(d1, 4); d2 += __shfl_xor(d2, 4);
            d0 += __shfl_xor(d0, 8); d1 += __shfl_xor(d1, 8); d2 += __shfl_xor(d2, 8);
            d0 += __shfl_xor(d0, 16); d1 += __shfl_xor(d1, 16); d2 += __shfl_xor(d2, 16);
            if (c == 0) {
                outp[n * 3 + 0] = x[n * 3 + 0] + d0;
                outp[n * 3 + 1] = x[n * 3 + 1] + d1;
                outp[n * 3 + 2] = x[n * 3 + 2] + d2;
            }
        }
    }

    if (l + 1 < NLAYER) {
        __syncthreads();
        // ---- fused nodepre for layer l+1: 4 groups of 32 lanes ----
        const int grp = tid >> 5;
        if (grp < 4) {
            const int lp = l + 1;
            if (grp == 0) {
                const float* W = Wq + lp * 1024;
                float acc = 0.f;
                for (int i = 0; i < 32; ++i) acc = fmaf(s_hn[i], W[i * 32 + c], acc);
                qout[n * 32 + c] = acc;
            } else if (grp == 1) {
                const float* W = Wm00 + lp * 1024;
                float acc = 0.f;
                for (int i = 0; i < 32; ++i) acc = fmaf(s_hn[i], W[i * 32 + c], acc);
                P00[n * 32 + c] = acc;
            } else if (grp == 2) {
                const float* W = Wm10 + lp * 1024;
                float acc = 0.f;
                for (int i = 0; i < 32; ++i) acc = fmaf(s_hn[i], W[i * 32 + c], acc);
                P10[n * 32 + c] = acc;
            } else {
                const float* W = Wm11 + lp * 1024;
                float px = 0.f, py = 0.f, pz = 0.f;
                for (int i = 0; i < 32; ++i) {
                    float w = W[i * 32 + c];
                    px = fmaf(s_hn[32 + i * 3 + 0], w, px);
                    py = fmaf(s_hn[32 + i * 3 + 1], w, py);
                    pz = fmaf(s_hn[32 + i * 3 + 2], w, pz);
                }
                float* pp = P11 + (size_t)n * 96 + c * 3;
                pp[0] = px; pp[1] = py; pp[2] = pz;
            }
        }
    }
}

// ---------------- launch ----------------
extern "C" void kernel_launch(void* const* d_in, const int* in_sizes, int n_in,
                              void* d_out, int out_size, void* d_ws, size_t ws_size,
                              hipStream_t stream) {
    const float* seq  = (const float*)d_in[0];
    const float* pair = (const float*)d_in[1];
    const float* bppm = (const float*)d_in[2];
    const float* x    = (const float*)d_in[3];
    const int*   src  = (const int*)d_in[4];
    const int*   dst  = (const int*)d_in[5];
    const float* Win0 = (const float*)d_in[6];
    const float* Win1 = (const float*)d_in[7];
    const float* Wr1  = (const float*)d_in[8];
    const float* br1  = (const float*)d_in[9];
    const float* Wr2  = (const float*)d_in[10];
    const float* br2  = (const float*)d_in[11];
    const float* Wm00 = (const float*)d_in[12];
    const float* Wm01 = (const float*)d_in[13];
    const float* Wm10 = (const float*)d_in[14];
    const float* Wm11 = (const float*)d_in[15];
    const float* Wq   = (const float*)d_in[16];
    const float* Ws0  = (const float*)d_in[17];
    const float* Ws1  = (const float*)d_in[18];
    const float* gam0 = (const float*)d_in[19];
    const float* bet0 = (const float*)d_in[20];
    const float* gam1 = (const float*)d_in[21];
    const float* Wout = (const float*)d_in[22];
    const int E = in_sizes[4];

    char* w = (char*)d_ws;
    auto alloc = [&](size_t nbytes) {
        void* p = (void*)w;
        w += (nbytes + 255) & ~(size_t)255;
        return p;
    };
    float* h0    = (float*)alloc((size_t)NN * CC * 4);
    float* h1    = (float*)alloc((size_t)NN * CC * 3 * 4);
    float* rhat  = (float*)alloc((size_t)E * 3 * 4);
    unsigned short* mbuf = (unsigned short*)alloc((size_t)E * 128 * 2);
    int* deg     = (int*)alloc((size_t)NN * 4);
    int* rowptr  = (int*)alloc((size_t)(NN + 1) * 4);
    int* cursor  = (int*)alloc((size_t)NN * 4);
    int* eperm   = (int*)alloc((size_t)E * 4);
    short* efb   = (short*)alloc((size_t)E * 160 * 2);
    short* W1p   = (short*)alloc((size_t)NLAYER * 5 * 4 * 64 * 8 * 2);
    short* W2p   = (short*)alloc((size_t)NLAYER * 2 * 8 * 64 * 8 * 2);
    float* qbuf  = (float*)alloc((size_t)NN * 32 * 4);
    float* P00   = (float*)alloc((size_t)NN * 32 * 4);
    float* P10   = (float*)alloc((size_t)NN * 32 * 4);
    float* P11   = (float*)alloc((size_t)NN * 96 * 4);

    const int TB = 256;
    k_init_h0<<<NN, 64, 0, stream>>>(seq, Win0, h0);
    k_init_h1<<<(NN * CC + TB - 1) / TB, TB, 0, stream>>>(x, Win1, h1, deg);
    k_edge_setup<<<(E + 3) / 4, 256, 0, stream>>>(src, dst, x, pair, bppm,
                                                  rhat, deg, efb, E);
    k_scan<<<1, 64, 0, stream>>>(deg, rowptr, cursor);
    k_scatter<<<(E + TB - 1) / TB, TB, 0, stream>>>(dst, rowptr, cursor, eperm, E);
    {
        int tot = NLAYER * 5 * 4 * 64 * 8 + NLAYER * 2 * 8 * 64 * 8;
        k_pack<<<(tot + TB - 1) / TB, TB, 0, stream>>>(Wr1, Wr2, W1p, W2p);
    }
    k_nodepre<<<NN / 8, 256, 0, stream>>>(0, h0, h1, Wq, Wm00, Wm10, Wm11,
                                          qbuf, P00, P10, P11);

    for (int l = 0; l < NLAYER; ++l) {
        k_radedge<<<(E + 63) / 64, 256, 0, stream>>>(l, E, src, rhat, efb, W1p, W2p,
                                                     br1, br2, Wm01, h1,
                                                     P00, P10, P11, eperm, mbuf);
        k_node<<<NN, 256, 0, stream>>>(l, rowptr, mbuf, qbuf, h0, h1,
                                       Ws0, Ws1, gam0, bet0, gam1,
                                       Wq, Wm00, Wm10, Wm11,
                                       qbuf, P00, P10, P11,
                                       x, Wout, (float*)d_out);
    }
}

// Round 5
// 822.395 us; speedup vs baseline: 1.4896x; 1.0149x over previous
//
#include <hip/hip_runtime.h>
#include <hip/hip_bf16.h>
#include <hip/hip_fp16.h>
#include <math.h>

#define BB 4
#define LL 512
#define D0 640
#define PP 128
#define CC 32
#define NLAYER 3
#define NN (BB*LL)      // 2048
#define RADIN 130

typedef __attribute__((ext_vector_type(8))) short bf16x8;
typedef __attribute__((ext_vector_type(4))) float f32x4;

__device__ __forceinline__ short f2b(float v) {
    __hip_bfloat16 h = __float2bfloat16(v);
    short s; __builtin_memcpy(&s, &h, 2); return s;
}
__device__ __forceinline__ unsigned short f2h(float v) {
    __half h = __float2half(v);
    unsigned short s; __builtin_memcpy(&s, &h, 2); return s;
}
__device__ __forceinline__ float h2f(unsigned short s) {
    __half h; __builtin_memcpy(&h, &s, 2); return __half2float(h);
}

// ---------------- fused init: h0 GEMV + h1/deg init + weight pack ----------------
// grid = 512 (h0) + 256 (h1+deg) + 216 (pack) = 984 blocks of 256
__global__ __launch_bounds__(256) void k_init(
    const float* __restrict__ seq, const float* __restrict__ Win0,
    const float* __restrict__ x, const float* __restrict__ Win1,
    const float* __restrict__ Wr1, const float* __restrict__ Wr2,
    float* __restrict__ h0, float* __restrict__ h1, int* __restrict__ deg,
    short* __restrict__ W1p, short* __restrict__ W2p)
{
    const int b = blockIdx.x;
    if (b < 512) {
        // h0 = seq @ Win0 : 4 nodes/block, one wave per node
        const int n = b * 4 + (threadIdx.x >> 6);
        const int lane = threadIdx.x & 63;
        const int c = lane & 31, half = lane >> 5;
        const float* s = seq + (size_t)n * D0;
        float acc = 0.f;
        const int i0 = half * (D0 / 2), i1 = i0 + (D0 / 2);
        for (int i = i0; i < i1; ++i) acc = fmaf(s[i], Win0[i * CC + c], acc);
        acc += __shfl_xor(acc, 32);
        if (lane < 32) h0[n * CC + c] = acc;
    } else if (b < 768) {
        const int idx = (b - 512) * 256 + threadIdx.x;   // 0..65535
        if (idx < NN) deg[idx] = 0;
        const int n = idx >> 5, c = idx & 31;
        const float w = Win1[c];
        const float* xp = x + n * 3;
        float* hp = h1 + (size_t)n * 96 + c * 3;
        hp[0] = xp[0] * w; hp[1] = xp[1] * w; hp[2] = xp[2] * w;
    } else {
        const int t = (b - 768) * 256 + threadIdx.x;
        const int tot1 = NLAYER * 5 * 4 * 64 * 8;        // 30720
        const int tot2 = NLAYER * 2 * 8 * 64 * 8;        // 24576
        if (t < tot1) {
            int j = t & 7; int r = t >> 3;
            int ln = r & 63; r >>= 6;
            int cb = r & 3; r >>= 2;
            int kb = r % 5; int l = r / 5;
            int row = kb * 32 + (ln >> 4) * 8 + j;
            int col = cb * 16 + (ln & 15);
            float v = (row < RADIN) ? Wr1[((size_t)l * RADIN + row) * 64 + col] : 0.f;
            W1p[t] = f2b(v);
        } else if (t < tot1 + tot2) {
            int t2 = t - tot1;
            int j = t2 & 7; int r = t2 >> 3;
            int ln = r & 63; r >>= 6;
            int cb = r & 7; r >>= 3;
            int kb = r & 1; int l = r >> 1;
            int row = kb * 32 + (ln >> 4) * 8 + j;
            int col = cb * 16 + (ln & 15);
            W2p[t2] = f2b(Wr2[((size_t)l * 64 + row) * 128 + col]);
        }
    }
}

// fused per-edge setup: geometry + degree count + bf16 ef row [E][160]
__global__ __launch_bounds__(256) void k_edge_setup(
    const int* __restrict__ src, const int* __restrict__ dst,
    const float* __restrict__ x,
    const float* __restrict__ pair, const float* __restrict__ bppm,
    float* __restrict__ rhat, int* __restrict__ deg,
    short* __restrict__ efb, int E)
{
    int e = blockIdx.x * 4 + (threadIdx.x >> 6);
    int lane = threadIdx.x & 63;
    if (e >= E) return;
    int s = src[e], d = dst[e];
    float dx = x[d * 3 + 0] - x[s * 3 + 0];
    float dy = x[d * 3 + 1] - x[s * 3 + 1];
    float dz = x[d * 3 + 2] - x[s * 3 + 2];
    float r = sqrtf(dx * dx + dy * dy + dz * dz + 1e-12f);
    float ir = 1.f / (r + 1e-8f);
    int b = s / LL, si = s % LL, di = d % LL;
    size_t prow = ((size_t)b * LL + si) * LL + di;
    const float* pr = pair + prow * PP;
    short* out = efb + (size_t)e * 160;
    out[lane] = f2b(pr[lane]);
    out[64 + lane] = f2b(pr[64 + lane]);
    if (lane < 32) {
        float v = 0.f;
        if (lane == 0) v = bppm[prow];
        else if (lane == 1) v = r;
        out[128 + lane] = f2b(v);
    }
    if (lane < 3) rhat[e * 3 + lane] = (lane == 0 ? dx : lane == 1 ? dy : dz) * ir;
    if (lane == 0) atomicAdd(&deg[d], 1);
}

// exclusive scan over N=2048 degrees with one wave; also zero cursor
__global__ __launch_bounds__(64) void k_scan(const int* __restrict__ deg,
                                             int* __restrict__ rowptr,
                                             int* __restrict__ cursor) {
    const int lane = threadIdx.x;          // 0..63
    const int base = lane * 32;            // 64*32 = 2048
    int loc[32]; int s = 0;
    for (int i = 0; i < 32; ++i) { loc[i] = deg[base + i]; s += loc[i]; }
    int pre = s;
    for (int off = 1; off < 64; off <<= 1) {
        int t = __shfl_up(pre, off);
        if (lane >= off) pre += t;
    }
    pre -= s;
    int run = pre;
    for (int i = 0; i < 32; ++i) { rowptr[base + i] = run; cursor[base + i] = 0; run += loc[i]; }
    if (lane == 63) rowptr[NN] = run;
}

// eperm[e] = dst-sorted slot of edge e (producer-side scatter position)
__global__ void k_scatter(const int* __restrict__ dst, const int* __restrict__ rowptr,
                          int* __restrict__ cursor, int* __restrict__ eperm, int E) {
    int e = blockIdx.x * blockDim.x + threadIdx.x;
    if (e >= E) return;
    int d = dst[e];
    int pos = atomicAdd(&cursor[d], 1);
    eperm[e] = rowptr[d] + pos;
}

// ---------------- layer-0 node precompute (adds P01 = h1 . Wm01) ----------------
__global__ __launch_bounds__(256) void k_nodepre(
    int l, const float* __restrict__ h0, const float* __restrict__ h1,
    const float* __restrict__ Wq, const float* __restrict__ Wm00,
    const float* __restrict__ Wm10, const float* __restrict__ Wm11,
    const float* __restrict__ Wm01,
    float* __restrict__ qbuf, float* __restrict__ P00,
    float* __restrict__ P10, float* __restrict__ P11, float* __restrict__ P01)
{
    __shared__ float sh0[8][32], sh1[8][96];
    const int c = threadIdx.x & 31, hw = threadIdx.x >> 5;
    const int n = blockIdx.x * 8 + hw;
    sh0[hw][c] = h0[n * CC + c];
    const float* hp = h1 + (size_t)n * 96 + c * 3;
    sh1[hw][c * 3 + 0] = hp[0]; sh1[hw][c * 3 + 1] = hp[1]; sh1[hw][c * 3 + 2] = hp[2];
    const float* WqL  = Wq   + l * 1024;
    const float* W00L = Wm00 + l * 1024;
    const float* W10L = Wm10 + l * 1024;
    const float* W11L = Wm11 + l * 1024;
    const float* W01L = Wm01 + l * 1024;
    float q = 0.f, p00 = 0.f, p10 = 0.f;
    float px = 0.f, py = 0.f, pz = 0.f;
    float ox = 0.f, oy = 0.f, oz = 0.f;
    for (int i = 0; i < 32; ++i) {
        float a = sh0[hw][i];
        q   = fmaf(a, WqL[i * 32 + c], q);
        p00 = fmaf(a, W00L[i * 32 + c], p00);
        p10 = fmaf(a, W10L[i * 32 + c], p10);
        float h1x = sh1[hw][i * 3 + 0], h1y = sh1[hw][i * 3 + 1], h1z = sh1[hw][i * 3 + 2];
        float w = W11L[i * 32 + c];
        px = fmaf(h1x, w, px); py = fmaf(h1y, w, py); pz = fmaf(h1z, w, pz);
        float w2 = W01L[i * 32 + c];
        ox = fmaf(h1x, w2, ox); oy = fmaf(h1y, w2, oy); oz = fmaf(h1z, w2, oz);
    }
    qbuf[n * 32 + c] = q; P00[n * 32 + c] = p00; P10[n * 32 + c] = p10;
    float* pp = P11 + (size_t)n * 96 + c * 3;
    pp[0] = px; pp[1] = py; pp[2] = pz;
    float* op = P01 + (size_t)n * 96 + c * 3;
    op[0] = ox; op[1] = oy; op[2] = oz;
}

// ---------------- fused radial MLP + edge epilogue ----------------
// Epilogue uses P01 trick: t1 = rhat . P01[src]  (no shfl loop, no h1 gather)
__global__ __launch_bounds__(256) void k_radedge(
    int l, int E,
    const int* __restrict__ src,
    const float* __restrict__ rhat,
    const short* __restrict__ efb,       // [E][160] bf16
    const short* __restrict__ W1p,       // [NL][5][4][64][8]
    const short* __restrict__ W2p,       // [NL][2][8][64][8]
    const float* __restrict__ br1,       // [NL][64]
    const float* __restrict__ br2,       // [NL][128]
    const float* __restrict__ P00,
    const float* __restrict__ P10,
    const float* __restrict__ P11,
    const float* __restrict__ P01,
    const int* __restrict__ eperm,
    unsigned short* __restrict__ mbuf)   // [E][128] fp16: [0:32)=m0, [32+c*3+d]=m1
{
    __shared__ short s_hid[4][16][72];            // per-wave [16][64] padded
    __shared__ unsigned short s_radh[64][130];    // radial out, fp16, padded
    const int lane = threadIdx.x & 63, wv = threadIdx.x >> 6;
    const int r16 = lane & 15, q4 = lane >> 4;
    const int eb = blockIdx.x * 64;
    const int e0 = eb + wv * 16;

    // ---- GEMM1: [16 x 160] @ [160 x 64] ----
    f32x4 acc0 = {0.f,0.f,0.f,0.f}, acc1 = {0.f,0.f,0.f,0.f};
    f32x4 acc2 = {0.f,0.f,0.f,0.f}, acc3 = {0.f,0.f,0.f,0.f};
    int row = e0 + r16; if (row >= E) row = E - 1;
    const short* arow = efb + (size_t)row * 160 + q4 * 8;
    const short* b1b = W1p + (size_t)l * (5 * 4 * 64 * 8) + lane * 8;
    for (int kb = 0; kb < 5; ++kb) {
        bf16x8 af = *(const bf16x8*)(arow + kb * 32);
        const short* bp = b1b + kb * (4 * 64 * 8);
        bf16x8 b0 = *(const bf16x8*)(bp);
        bf16x8 b1v = *(const bf16x8*)(bp + 64 * 8);
        bf16x8 b2v = *(const bf16x8*)(bp + 2 * 64 * 8);
        bf16x8 b3v = *(const bf16x8*)(bp + 3 * 64 * 8);
        acc0 = __builtin_amdgcn_mfma_f32_16x16x32_bf16(af, b0,  acc0, 0, 0, 0);
        acc1 = __builtin_amdgcn_mfma_f32_16x16x32_bf16(af, b1v, acc1, 0, 0, 0);
        acc2 = __builtin_amdgcn_mfma_f32_16x16x32_bf16(af, b2v, acc2, 0, 0, 0);
        acc3 = __builtin_amdgcn_mfma_f32_16x16x32_bf16(af, b3v, acc3, 0, 0, 0);
    }
    {
        f32x4 a[4] = {acc0, acc1, acc2, acc3};
        for (int cb = 0; cb < 4; ++cb) {
            int col = cb * 16 + r16;
            float b = br1[l * 64 + col];
            for (int i = 0; i < 4; ++i) {
                float v = fmaxf(a[cb][i] + b, 0.f);
                s_hid[wv][q4 * 4 + i][col] = f2b(v);
            }
        }
    }
    // ---- GEMM2: [16 x 64] @ [64 x 128] ----
    f32x4 o[8];
    for (int cb = 0; cb < 8; ++cb) { o[cb].x=0.f; o[cb].y=0.f; o[cb].z=0.f; o[cb].w=0.f; }
    const short* b2b = W2p + (size_t)l * (2 * 8 * 64 * 8) + lane * 8;
    for (int kb = 0; kb < 2; ++kb) {
        bf16x8 af = *(const bf16x8*)(&s_hid[wv][r16][kb * 32 + q4 * 8]);
        const short* bp = b2b + kb * (8 * 64 * 8);
        for (int cb = 0; cb < 8; ++cb) {
            bf16x8 bf = *(const bf16x8*)(bp + cb * (64 * 8));
            o[cb] = __builtin_amdgcn_mfma_f32_16x16x32_bf16(af, bf, o[cb], 0, 0, 0);
        }
    }
    for (int cb = 0; cb < 8; ++cb) {
        int col = cb * 16 + r16;
        float b = br2[l * 128 + col];
        for (int i = 0; i < 4; ++i) {
            s_radh[wv * 16 + q4 * 4 + i][col] = f2h(o[cb][i] + b);
        }
    }
    __syncthreads();

    // ---- edge epilogue: half-wave per edge, 8 edges per half-wave ----
    const int hw = threadIdx.x >> 5;     // 0..7
    const int c = lane & 31;
    for (int it = 0; it < 8; ++it) {
        const int el = hw * 8 + it;
        const int e = eb + el;
        if (e >= E) break;
        const int s = src[e];
        const float r0 = rhat[e * 3 + 0], r1 = rhat[e * 3 + 1], r2 = rhat[e * 3 + 2];
        const float w00 = h2f(s_radh[el][c]),      w01 = h2f(s_radh[el][32 + c]);
        const float w10 = h2f(s_radh[el][64 + c]), w11 = h2f(s_radh[el][96 + c]);
        const float* q01 = P01 + (size_t)s * 96 + c * 3;
        const float t1 = r0 * q01[0] + r1 * q01[1] + r2 * q01[2];
        const float m0 = fmaf(w00, P00[s * 32 + c], w01 * t1);
        const float u10 = w10 * P10[s * 32 + c];
        const float* pp = P11 + (size_t)s * 96 + c * 3;
        unsigned short* mp = mbuf + (size_t)eperm[e] * 128;
        mp[c] = f2h(m0);
        mp[32 + c * 3 + 0] = f2h(fmaf(w11, pp[0], u10 * r0));
        mp[32 + c * 3 + 1] = f2h(fmaf(w11, pp[1], u10 * r1));
        mp[32 + c * 3 + 2] = f2h(fmaf(w11, pp[2], u10 * r2));
    }
}

// ---------------- node update kernel (per layer) ----------------
__global__ __launch_bounds__(256) void k_node(
    int l, const int* __restrict__ rowptr,
    const unsigned short* __restrict__ mbuf,
    const float* __restrict__ qbuf_in,
    float* __restrict__ h0, float* __restrict__ h1,
    const float* __restrict__ Ws0, const float* __restrict__ Ws1,
    const float* __restrict__ gam0, const float* __restrict__ bet0,
    const float* __restrict__ gam1,
    const float* __restrict__ Wq, const float* __restrict__ Wm00,
    const float* __restrict__ Wm10, const float* __restrict__ Wm11,
    const float* __restrict__ Wm01,
    float* __restrict__ qout, float* __restrict__ P00,
    float* __restrict__ P10, float* __restrict__ P11, float* __restrict__ P01,
    const float* __restrict__ x, const float* __restrict__ Wout,
    float* __restrict__ outp)
{
    const int n = blockIdx.x;
    const int tid = threadIdx.x;
    const int hw = tid >> 5;        // 0..7
    const int c = tid & 31;
    __shared__ float s_part[8][32][6];   // per-half-wave online-softmax partials
    __shared__ float s_a0[32], s_a1[96];
    __shared__ float s_hn[128];          // h0n[0:32), h1n[32+c*3+d]

    const float qc = qbuf_in[n * 32 + c];
    const int st = rowptr[n], en = rowptr[n + 1];

    float m_run = -INFINITY, l_run = 0.f;
    float a0 = 0.f, a1x = 0.f, a1y = 0.f, a1z = 0.f;
    for (int idx = st + hw; idx < en; idx += 8) {
        const unsigned short* row = mbuf + (size_t)idx * 128;
        const float kc = h2f(row[c]);
        const float mv0 = h2f(row[32 + c * 3 + 0]);
        const float mv1 = h2f(row[32 + c * 3 + 1]);
        const float mv2 = h2f(row[32 + c * 3 + 2]);
        float p = qc * kc;
        p += __shfl_xor(p, 1); p += __shfl_xor(p, 2); p += __shfl_xor(p, 4);
        const float logit = p * 0.35355339059327373f;   // 1/sqrt(8)
        const float mn = fmaxf(m_run, logit);
        const float sc = __expf(m_run - mn);
        const float w  = __expf(logit - mn);
        l_run = fmaf(l_run, sc, w);
        a0  = fmaf(a0,  sc, w * kc);
        a1x = fmaf(a1x, sc, w * mv0);
        a1y = fmaf(a1y, sc, w * mv1);
        a1z = fmaf(a1z, sc, w * mv2);
        m_run = mn;
    }
    s_part[hw][c][0] = m_run; s_part[hw][c][1] = l_run;
    s_part[hw][c][2] = a0;
    s_part[hw][c][3] = a1x; s_part[hw][c][4] = a1y; s_part[hw][c][5] = a1z;
    __syncthreads();

    if (tid < 32) {
        float M = s_part[0][c][0], L = s_part[0][c][1], A0 = s_part[0][c][2];
        float Ax = s_part[0][c][3], Ay = s_part[0][c][4], Az = s_part[0][c][5];
        for (int k = 1; k < 8; ++k) {
            const float m2 = s_part[k][c][0];
            if (m2 == -INFINITY) continue;
            const float mn = fmaxf(M, m2);
            const float sa = (M == -INFINITY) ? 0.f : __expf(M - mn);
            const float sb = __expf(m2 - mn);
            L  = L  * sa + s_part[k][c][1] * sb;
            A0 = A0 * sa + s_part[k][c][2] * sb;
            Ax = Ax * sa + s_part[k][c][3] * sb;
            Ay = Ay * sa + s_part[k][c][4] * sb;
            Az = Az * sa + s_part[k][c][5] * sb;
            M = mn;
        }
        const float inv = 1.0f / (L + 1e-9f);
        s_a0[c] = A0 * inv;
        s_a1[c * 3 + 0] = Ax * inv;
        s_a1[c * 3 + 1] = Ay * inv;
        s_a1[c * 3 + 2] = Az * inv;
    }
    __syncthreads();

    if (tid < 32) {
        // ---- h0 update + LayerNorm ----
        float x0 = h0[n * CC + c];
        {
            const float* W = Ws0 + l * 1024;
            for (int i = 0; i < 32; ++i) x0 = fmaf(s_a0[i], W[i * 32 + c], x0);
        }
        float mu = x0;
        mu += __shfl_xor(mu, 1); mu += __shfl_xor(mu, 2); mu += __shfl_xor(mu, 4);
        mu += __shfl_xor(mu, 8); mu += __shfl_xor(mu, 16);
        mu *= (1.f / 32.f);
        float sq = x0 * x0;
        sq += __shfl_xor(sq, 1); sq += __shfl_xor(sq, 2); sq += __shfl_xor(sq, 4);
        sq += __shfl_xor(sq, 8); sq += __shfl_xor(sq, 16);
        float var = sq * (1.f / 32.f) - mu * mu;
        float h0n = (x0 - mu) * rsqrtf(var + 1e-5f) * gam0[l * 32 + c] + bet0[l * 32 + c];
        s_hn[c] = h0n;
        if (l + 1 < NLAYER) h0[n * CC + c] = h0n;

        // ---- h1 update + norm-gating ----
        const float* hp = h1 + (size_t)n * 96 + c * 3;
        float v0 = hp[0], v1 = hp[1], v2 = hp[2];
        {
            const float* W = Ws1 + l * 1024;
            for (int i = 0; i < 32; ++i) {
                float w = W[i * 32 + c];
                v0 = fmaf(s_a1[i * 3 + 0], w, v0);
                v1 = fmaf(s_a1[i * 3 + 1], w, v1);
                v2 = fmaf(s_a1[i * 3 + 2], w, v2);
            }
        }
        float nrm = sqrtf(v0 * v0 + v1 * v1 + v2 * v2 + 1e-12f);
        float mu2 = nrm;
        mu2 += __shfl_xor(mu2, 1); mu2 += __shfl_xor(mu2, 2); mu2 += __shfl_xor(mu2, 4);
        mu2 += __shfl_xor(mu2, 8); mu2 += __shfl_xor(mu2, 16);
        mu2 *= (1.f / 32.f);
        float sq2 = nrm * nrm;
        sq2 += __shfl_xor(sq2, 1); sq2 += __shfl_xor(sq2, 2); sq2 += __shfl_xor(sq2, 4);
        sq2 += __shfl_xor(sq2, 8); sq2 += __shfl_xor(sq2, 16);
        float var2 = sq2 * (1.f / 32.f) - mu2 * mu2;
        float nln = (nrm - mu2) * rsqrtf(var2 + 1e-5f) * gam1[l * 32 + c];
        float scl = nln / (nrm + 1e-8f);
        float w0 = v0 * scl, w1 = v1 * scl, w2 = v2 * scl;
        s_hn[32 + c * 3 + 0] = w0;
        s_hn[32 + c * 3 + 1] = w1;
        s_hn[32 + c * 3 + 2] = w2;
        if (l + 1 < NLAYER) {
            float* hq = h1 + (size_t)n * 96 + c * 3;
            hq[0] = w0; hq[1] = w1; hq[2] = w2;
        } else {
            // ---- fused output projection: out = x + h1n . Wout ----
            const float wo = Wout[c];
            float d0 = w0 * wo, d1 = w1 * wo, d2 = w2 * wo;
            d0 += __shfl_xor(d0, 1); d1 += __shfl_xor(d1, 1); d2 += __shfl_xor(d2, 1);
            d0 += __shfl_xor(d0, 2); d1 += __shfl_xor(d1, 2); d2 += __shfl_xor(d2, 2);
            d0 += __shfl_xor(d0, 4); d1 += __shfl_xor(d1, 4); d2 += __shfl_xor(d2, 4);
            d0 += __shfl_xor(d0, 8); d1 += __shfl_xor(d1, 8); d2 += __shfl_xor(d2, 8);
            d0 += __shfl_xor(d0, 16); d1 += __shfl_xor(d1, 16); d2 += __shfl_xor(d2, 16);
            if (c == 0) {
                outp[n * 3 + 0] = x[n * 3 + 0] + d0;
                outp[n * 3 + 1] = x[n * 3 + 1] + d1;
                outp[n * 3 + 2] = x[n * 3 + 2] + d2;
            }
        }
    }

    if (l + 1 < NLAYER) {
        __syncthreads();
        // ---- fused nodepre for layer l+1: 5 groups of 32 lanes ----
        const int grp = tid >> 5;
        const int lp = l + 1;
        if (grp == 0) {
            const float* W = Wq + lp * 1024;
            float acc = 0.f;
            for (int i = 0; i < 32; ++i) acc = fmaf(s_hn[i], W[i * 32 + c], acc);
            qout[n * 32 + c] = acc;
        } else if (grp == 1) {
            const float* W = Wm00 + lp * 1024;
            float acc = 0.f;
            for (int i = 0; i < 32; ++i) acc = fmaf(s_hn[i], W[i * 32 + c], acc);
            P00[n * 32 + c] = acc;
        } else if (grp == 2) {
            const float* W = Wm10 + lp * 1024;
            float acc = 0.f;
            for (int i = 0; i < 32; ++i) acc = fmaf(s_hn[i], W[i * 32 + c], acc);
            P10[n * 32 + c] = acc;
        } else if (grp == 3) {
            const float* W = Wm11 + lp * 1024;
            float px = 0.f, py = 0.f, pz = 0.f;
            for (int i = 0; i < 32; ++i) {
                float w = W[i * 32 + c];
                px = fmaf(s_hn[32 + i * 3 + 0], w, px);
                py = fmaf(s_hn[32 + i * 3 + 1], w, py);
                pz = fmaf(s_hn[32 + i * 3 + 2], w, pz);
            }
            float* pp = P11 + (size_t)n * 96 + c * 3;
            pp[0] = px; pp[1] = py; pp[2] = pz;
        } else if (grp == 4) {
            const float* W = Wm01 + lp * 1024;
            float px = 0.f, py = 0.f, pz = 0.f;
            for (int i = 0; i < 32; ++i) {
                float w = W[i * 32 + c];
                px = fmaf(s_hn[32 + i * 3 + 0], w, px);
                py = fmaf(s_hn[32 + i * 3 + 1], w, py);
                pz = fmaf(s_hn[32 + i * 3 + 2], w, pz);
            }
            float* pp = P01 + (size_t)n * 96 + c * 3;
            pp[0] = px; pp[1] = py; pp[2] = pz;
        }
    }
}

// ---------------- launch ----------------
extern "C" void kernel_launch(void* const* d_in, const int* in_sizes, int n_in,
                              void* d_out, int out_size, void* d_ws, size_t ws_size,
                              hipStream_t stream) {
    const float* seq  = (const float*)d_in[0];
    const float* pair = (const float*)d_in[1];
    const float* bppm = (const float*)d_in[2];
    const float* x    = (const float*)d_in[3];
    const int*   src  = (const int*)d_in[4];
    const int*   dst  = (const int*)d_in[5];
    const float* Win0 = (const float*)d_in[6];
    const float* Win1 = (const float*)d_in[7];
    const float* Wr1  = (const float*)d_in[8];
    const float* br1  = (const float*)d_in[9];
    const float* Wr2  = (const float*)d_in[10];
    const float* br2  = (const float*)d_in[11];
    const float* Wm00 = (const float*)d_in[12];
    const float* Wm01 = (const float*)d_in[13];
    const float* Wm10 = (const float*)d_in[14];
    const float* Wm11 = (const float*)d_in[15];
    const float* Wq   = (const float*)d_in[16];
    const float* Ws0  = (const float*)d_in[17];
    const float* Ws1  = (const float*)d_in[18];
    const float* gam0 = (const float*)d_in[19];
    const float* bet0 = (const float*)d_in[20];
    const float* gam1 = (const float*)d_in[21];
    const float* Wout = (const float*)d_in[22];
    const int E = in_sizes[4];

    char* w = (char*)d_ws;
    auto alloc = [&](size_t nbytes) {
        void* p = (void*)w;
        w += (nbytes + 255) & ~(size_t)255;
        return p;
    };
    float* h0    = (float*)alloc((size_t)NN * CC * 4);
    float* h1    = (float*)alloc((size_t)NN * CC * 3 * 4);
    float* rhat  = (float*)alloc((size_t)E * 3 * 4);
    unsigned short* mbuf = (unsigned short*)alloc((size_t)E * 128 * 2);
    int* deg     = (int*)alloc((size_t)NN * 4);
    int* rowptr  = (int*)alloc((size_t)(NN + 1) * 4);
    int* cursor  = (int*)alloc((size_t)NN * 4);
    int* eperm   = (int*)alloc((size_t)E * 4);
    short* efb   = (short*)alloc((size_t)E * 160 * 2);
    short* W1p   = (short*)alloc((size_t)NLAYER * 5 * 4 * 64 * 8 * 2);
    short* W2p   = (short*)alloc((size_t)NLAYER * 2 * 8 * 64 * 8 * 2);
    float* qbuf  = (float*)alloc((size_t)NN * 32 * 4);
    float* P00   = (float*)alloc((size_t)NN * 32 * 4);
    float* P10   = (float*)alloc((size_t)NN * 32 * 4);
    float* P11   = (float*)alloc((size_t)NN * 96 * 4);
    float* P01   = (float*)alloc((size_t)NN * 96 * 4);

    const int TB = 256;
    k_init<<<984, 256, 0, stream>>>(seq, Win0, x, Win1, Wr1, Wr2,
                                    h0, h1, deg, W1p, W2p);
    k_edge_setup<<<(E + 3) / 4, 256, 0, stream>>>(src, dst, x, pair, bppm,
                                                  rhat, deg, efb, E);
    k_scan<<<1, 64, 0, stream>>>(deg, rowptr, cursor);
    k_scatter<<<(E + TB - 1) / TB, TB, 0, stream>>>(dst, rowptr, cursor, eperm, E);
    k_nodepre<<<NN / 8, 256, 0, stream>>>(0, h0, h1, Wq, Wm00, Wm10, Wm11, Wm01,
                                          qbuf, P00, P10, P11, P01);

    for (int l = 0; l < NLAYER; ++l) {
        k_radedge<<<(E + 63) / 64, 256, 0, stream>>>(l, E, src, rhat, efb, W1p, W2p,
                                                     br1, br2,
                                                     P00, P10, P11, P01, eperm, mbuf);
        k_node<<<NN, 256, 0, stream>>>(l, rowptr, mbuf, qbuf, h0, h1,
                                       Ws0, Ws1, gam0, bet0, gam1,
                                       Wq, Wm00, Wm10, Wm11, Wm01,
                                       qbuf, P00, P10, P11, P01,
                                       x, Wout, (float*)d_out);
    }
}